// Round 16
// baseline (8768.922 us; speedup 1.0000x reference)
//
#include <hip/hip_runtime.h>
#include <cstdint>

constexpr int Bn = 128, Tn = 1024, Dn = 64, Hn = 256, On = 128;

typedef __fp16 h2 __attribute__((ext_vector_type(2)));
typedef __fp16 half8_t __attribute__((ext_vector_type(8)));
typedef float f32x4 __attribute__((ext_vector_type(4)));
typedef unsigned short u16;

__device__ __forceinline__ float fast_tanh(float x) {
  float e = __expf(2.0f * x);
  return 1.0f - 2.0f / (e + 1.0f);
}
__device__ __forceinline__ h2 pk2(float a, float b) {
  h2 r; r.x = (__fp16)a; r.y = (__fp16)b; return r;
}
__device__ __forceinline__ unsigned h2bits(h2 v) { return __builtin_bit_cast(unsigned, v); }
__device__ __forceinline__ u16 f2hb(float f) {
  __fp16 h = (__fp16)f; return __builtin_bit_cast(u16, h);
}
__device__ __forceinline__ float hb2f(u16 b) {
  return (float)__builtin_bit_cast(__fp16, b);
}

// ---------------------------------------------------------------------------
// MFMA broadcast matvec (rounds 10-15, absmax-verified). Every lane's A-frag
// covers k = 32kt + 8*(l>>4) + e, independent of l&15 -> all 16 A-rows equal
// h -> D reg 0 = h @ W for this lane's column. A and B use the SAME k-map so
// any intra-tile k-permutation cancels. B-frags (weights) live in AGPRs
// (natural 64/64 split at 1024 threads); MFMA reads them natively (isa §10).
// K=256 version: source in the 20-stride slice layout; 2 chains (32 cols).
// ---------------------------------------------------------------------------
__device__ __forceinline__ void mfma_step(const u16* hcB, int oh, int ol,
                                          const half8_t (&wfr)[16],
                                          float& v0, float& v1) {
  uint2 ra[8], rb[8];
  #pragma unroll
  for (int kt = 0; kt < 8; ++kt) {
    const u16* ap = hcB + 40 * kt + 20 * oh + 8 * ol;
    ra[kt] = *(const uint2*)ap;
    rb[kt] = *(const uint2*)(ap + 4);
  }
  f32x4 ac0 = {0.f, 0.f, 0.f, 0.f}, ac1 = {0.f, 0.f, 0.f, 0.f};
  #pragma unroll
  for (int kt = 0; kt < 8; ++kt) {
    half8_t af = __builtin_bit_cast(
        half8_t, make_uint4(ra[kt].x, ra[kt].y, rb[kt].x, rb[kt].y));
    ac0 = __builtin_amdgcn_mfma_f32_16x16x32_f16(af, wfr[kt], ac0, 0, 0, 0);
    ac1 = __builtin_amdgcn_mfma_f32_16x16x32_f16(af, wfr[8 + kt], ac1, 0, 0, 0);
  }
  v0 = ac0[0];
  v1 = ac1[0];
}
// K=64 version: source row in plain stride-64-half layout (16B aligned);
// uses wfr[0],[1] (chain 0) and wfr[8],[9] (chain 1). Verified round 13.
__device__ __forceinline__ void mv64mf(const u16* xrow, int lq,
                                       const half8_t (&wfr)[16],
                                       float& v0, float& v1) {
  uint4 r0 = *(const uint4*)(xrow + lq);
  uint4 r1 = *(const uint4*)(xrow + 32 + lq);
  half8_t af0 = __builtin_bit_cast(half8_t, r0);
  half8_t af1 = __builtin_bit_cast(half8_t, r1);
  f32x4 a0 = {0.f, 0.f, 0.f, 0.f}, a1 = {0.f, 0.f, 0.f, 0.f};
  a0 = __builtin_amdgcn_mfma_f32_16x16x32_f16(af0, wfr[0], a0, 0, 0, 0);
  a0 = __builtin_amdgcn_mfma_f32_16x16x32_f16(af1, wfr[1], a0, 0, 0, 0);
  a1 = __builtin_amdgcn_mfma_f32_16x16x32_f16(af0, wfr[8], a1, 0, 0, 0);
  a1 = __builtin_amdgcn_mfma_f32_16x16x32_f16(af1, wfr[9], a1, 0, 0, 0);
  v0 = a0[0];
  v1 = a1[0];
}

// LDS h layout (f16): 16 slices x (16 data + 4 pad) halfs; slice stride 40 B.
// ---------------------------------------------------------------------------
// Fused pipeline, 256 WGs x 1024 threads == 1 block/CU. Round-16 change vs
// round 15 (1078 us): DENSE waves switch from v_dot (+64 accvgpr_read + 32
// DPP per slice -- the AGPR-read tax at the 64-arch ceiling) to the SAME
// MFMA broadcast matvec as serial. Per dense slice: ~350 VALU ops -> 16 MFMA
// + 16 ds_read. A/B question this answers: is the 1.05us step contention
// (dense VALU sharing the SIMD) or 16-wave barrier population? Dense-MFMA
// correctness was verified in round 13 (passed absmax; slow only due to
// 512-thr spill, absent here).
//   role A  (blocks 0..127): waves 0-7 serial scan1 (Wh1 frags in AGPR);
//       waves 8-15 dense: stage x + u1 = x@Wx1+b1 rows via mv64mf.
//   role BC (blocks 128..255): waves 0-7 serial scan2 (Wh2);
//       waves 8-15 dense u2 = h1@Wx2+b2 via mfma_step.
//   Each wave owns 32 output cols: jc = 32*(w&7) + (l&15), chains at jc and
//   jc+16. wfr[16] = 64 regs -> AGPR half of the 1024-thr 64/64 split.
// ---------------------------------------------------------------------------
__global__ __launch_bounds__(1024)
__attribute__((amdgpu_waves_per_eu(4, 4))) void stage1_kernel(
    const float* __restrict__ x,    // [B,T,64] f32
    const float* __restrict__ Wx1,  // [64,256] f32
    const float* __restrict__ Wh1,  // [256,256] f32
    const float* __restrict__ b1,   // [256]
    const float* __restrict__ Wx2,  // [256,256] f32
    const float* __restrict__ b2,   // [256]
    const float* __restrict__ Wh2,  // [256,256] f32
    u16* __restrict__ h1b16,        // [B,T,256] f16 h1 (A -> BC channel)
    int* __restrict__ flags,        // [B]  A -> BC progress (32-step chunks)
    float* __restrict__ hfinal) {   // [B,256] f32 (role BC output)
  __shared__ alignas(16) u16 smemU[19584];  // 38.25 KB
  const int tid = threadIdx.x;
  const unsigned bid = blockIdx.x;
  const bool roleA = (bid < (unsigned)Bn);
  const bool serialG = (tid < 512);

  // T5 (null in round 15, harmless): serial waves keep priority 1.
  if (serialG) __builtin_amdgcn_s_setprio(1);

  const int w_ = tid >> 6;            // wave 0..15
  const int l = tid & 63;
  const int oh = (l >> 5) & 1;
  const int ol = (l >> 4) & 1;
  const int lq = 8 * (l >> 4);        // k-oct offset (halfs)
  const int jc = 32 * (w_ & 7) + (l & 15);  // wave's chain-0 column
  const int woff0 = 40 * w_ + (l & 15);     // serial h-state write offset
  const int lt = tid & 511;           // index within wave-group

  // ---- weights: frag (g,kt): lane l holds W[32kt+lq+e][jc+16g] ----
  half8_t wfr[16];
  #pragma unroll
  for (int i = 0; i < 16; ++i) wfr[i] = half8_t{0};
  {
    const float* Wsrc = roleA ? (serialG ? Wh1 : Wx1)
                              : (serialG ? Wh2 : Wx2);
    const int kmax = (roleA && !serialG) ? 2 : 8;
    for (int g = 0; g < 2; ++g)
      for (int kt = 0; kt < kmax; ++kt) {
        const float* wp = Wsrc + (size_t)(32 * kt + lq) * Hn + jc + 16 * g;
        half8_t f;
        #pragma unroll
        for (int e = 0; e < 8; ++e) f[e] = (__fp16)wp[(size_t)e * Hn];
        wfr[g * 8 + kt] = f;
      }
  }
  // dense biases for this wave's 2 columns
  float bjd0 = 0.f, bjd1 = 0.f;
  if (!serialG) {
    const float* bb = roleA ? b1 : b2;
    bjd0 = bb[jc];
    bjd1 = bb[jc + 16];
  }

  if (roleA) {
    // ==================== ROLE A ====================
    const int b = bid;
    const float* xb = x + (size_t)b * Tn * Dn;
    u16* hb = h1b16 + (size_t)b * Tn * Hn;
    u16* hcH = smemU;            // 640 halfs: 2 x 320 h-state
    u16* xs = smemU + 640;       // 2048 halfs: x chunk [32][64] f16
    u16* u1S = smemU + 2688;     // 8704 halfs: u1 [32][272]

    if (serialG)
      for (int i = tid; i < 640; i += 512) hcH[i] = 0;
    __syncthreads();

    for (int ch = 0; ch < 32; ++ch) {
      // pre1: dense stages x chunk ch -> xs (f16)
      if (!serialG) {
        const float* xsrc = xb + (size_t)ch * 2048 + (lt >> 4) * 64 + (lt & 15) * 4;
        float4 f = *(const float4*)xsrc;
        *(uint2*)(xs + (lt >> 4) * 64 + (lt & 15) * 4) =
            make_uint2(h2bits(pk2(f.x, f.y)), h2bits(pk2(f.z, f.w)));
      }
      __syncthreads();
      // pre2: dense computes u1 row 0
      if (!serialG) {
        float v0, v1;
        mv64mf(xs, lq, wfr, v0, v1);
        if (l < 16) {
          u1S[jc] = f2hb(v0 + bjd0);
          u1S[jc + 16] = f2hb(v1 + bjd1);
        }
      }
      __syncthreads();
      // 32 slices: serial step s || dense u1 row s+1
      for (int g4 = 0; g4 < 4; ++g4) {
        u16 hreg0[8], hreg1[8];
        #pragma unroll
        for (int s8 = 0; s8 < 8; ++s8) {
          const int s = g4 * 8 + s8;
          if (serialG) {
            const int cu = s & 1, nx = cu ^ 1;
            float uv0 = hb2f(u1S[s * 272 + jc]);
            float uv1 = hb2f(u1S[s * 272 + jc + 16]);
            float v0, v1;
            mfma_step(hcH + cu * 320, oh, ol, wfr, v0, v1);
            u16 h0 = f2hb(fast_tanh(v0 + uv0));
            u16 h1 = f2hb(fast_tanh(v1 + uv1));
            if (l < 16) {
              hcH[nx * 320 + woff0] = h0;
              hcH[nx * 320 + woff0 + 20] = h1;
            }
            hreg0[s8] = h0;
            hreg1[s8] = h1;
            if (s8 == 7 && l < 16) {
              u16* d0 = hb + (size_t)(32 * ch + s - 7) * Hn + jc;
              #pragma unroll
              for (int i = 0; i < 8; ++i) {
                d0[i * Hn] = hreg0[i];
                d0[i * Hn + 16] = hreg1[i];
              }
            }
          } else if (s < 31) {
            float v0, v1;
            mv64mf(xs + (s + 1) * 64, lq, wfr, v0, v1);
            if (l < 16) {
              u1S[(s + 1) * 272 + jc] = f2hb(v0 + bjd0);
              u1S[(s + 1) * 272 + jc + 16] = f2hb(v1 + bjd1);
            }
          }
          __syncthreads();  // drains vmem (incl. h1 stores at s8==7)
        }
      }
      if (tid == 0)
        __hip_atomic_store(flags + b, ch + 1, __ATOMIC_RELEASE,
                           __HIP_MEMORY_SCOPE_AGENT);
    }
  } else {
    // ==================== ROLE BC ====================
    const int b = bid - Bn;
    const u16* hb1 = h1b16 + (size_t)b * Tn * Hn;
    u16* hsH = smemU;            // [32][320] halfs (h1 staging, slice layout)
    u16* u2S = smemU + 10240;    // [32][272] halfs (u2)
    u16* hcU = smemU + 18944;    // 2 x 320 halfs (h2 state)
    u16* ldst = hsH + (lt >> 4) * 320 + 20 * (lt & 15);

    if (serialG)
      for (int i = tid; i < 640; i += 512) hcU[i] = 0;
    __syncthreads();

    for (int ch = 0; ch < 32; ++ch) {
      if (!serialG && lt == 0) {
        while (__hip_atomic_load(flags + b, __ATOMIC_ACQUIRE,
                                 __HIP_MEMORY_SCOPE_AGENT) < ch + 1)
          __builtin_amdgcn_s_sleep(8);
      }
      __syncthreads();  // flag acquired
      if (!serialG) {   // stage h1 chunk [32][256] -> hsH (slice layout)
        const uint4* src =
            (const uint4*)(hb1 + (size_t)(ch * 32 + (lt >> 4)) * Hn + 16 * (lt & 15));
        uint4 v0 = src[0], v1 = src[1];
        ((uint2*)ldst)[0] = make_uint2(v0.x, v0.y);
        ((uint2*)ldst)[1] = make_uint2(v0.z, v0.w);
        ((uint2*)ldst)[2] = make_uint2(v1.x, v1.y);
        ((uint2*)ldst)[3] = make_uint2(v1.z, v1.w);
      }
      __syncthreads();  // staged
      if (!serialG) {   // u2 row 0
        float v0, v1;
        mfma_step(hsH, oh, ol, wfr, v0, v1);
        if (l < 16) {
          u2S[jc] = f2hb(v0 + bjd0);
          u2S[jc + 16] = f2hb(v1 + bjd1);
        }
      }
      __syncthreads();  // row 0 visible

      for (int g4 = 0; g4 < 4; ++g4) {
        #pragma unroll
        for (int s8 = 0; s8 < 8; ++s8) {
          const int s = g4 * 8 + s8;
          if (serialG) {
            const int cu = s & 1, nx = cu ^ 1;
            float uv0 = hb2f(u2S[s * 272 + jc]);
            float uv1 = hb2f(u2S[s * 272 + jc + 16]);
            float v0, v1;
            mfma_step(hcU + cu * 320, oh, ol, wfr, v0, v1);
            if (l < 16) {
              hcU[nx * 320 + woff0] = f2hb(fast_tanh(v0 + uv0));
              hcU[nx * 320 + woff0 + 20] = f2hb(fast_tanh(v1 + uv1));
            }
          } else if (s < 31) {
            float v0, v1;
            mfma_step(hsH + (s + 1) * 320, oh, ol, wfr, v0, v1);
            if (l < 16) {
              u2S[(s + 1) * 272 + jc] = f2hb(v0 + bjd0);
              u2S[(s + 1) * 272 + jc + 16] = f2hb(v1 + bjd1);
            }
          }
          __syncthreads();
        }
      }
    }
    if (tid < Hn)
      hfinal[(size_t)b * Hn + tid] = hb2f(hcU[(tid >> 4) * 20 + (tid & 15)]);
  }
}

// ---------------------------------------------------------------------------
// Head: out = softmax(h2_T @ Wd + bd). f32, unchanged.
// ---------------------------------------------------------------------------
__global__ __launch_bounds__(128) void head_kernel(
    const float* __restrict__ hfinal, const float* __restrict__ Wd,
    const float* __restrict__ bd, float* __restrict__ out) {
  __shared__ float hrow[Hn];
  __shared__ float red[On];
  const int o = threadIdx.x;
  const int b = blockIdx.x;
  hrow[o] = hfinal[(size_t)b * Hn + o];
  hrow[o + 128] = hfinal[(size_t)b * Hn + 128 + o];
  __syncthreads();
  float acc = bd[o];
  #pragma unroll 8
  for (int k = 0; k < Hn; ++k) acc = fmaf(hrow[k], Wd[(size_t)k * On + o], acc);
  red[o] = acc;
  __syncthreads();
  #pragma unroll
  for (int s = 64; s > 0; s >>= 1) {
    if (o < s) red[o] = fmaxf(red[o], red[o + s]);
    __syncthreads();
  }
  const float mx = red[0];
  __syncthreads();
  const float e = __expf(acc - mx);
  red[o] = e;
  __syncthreads();
  #pragma unroll
  for (int s = 64; s > 0; s >>= 1) {
    if (o < s) red[o] += red[o + s];
    __syncthreads();
  }
  out[(size_t)b * On + o] = e / red[0];
}

// ---------------------------------------------------------------------------
extern "C" void kernel_launch(void* const* d_in, const int* in_sizes, int n_in,
                              void* d_out, int out_size, void* d_ws, size_t ws_size,
                              hipStream_t stream) {
  const float* x   = (const float*)d_in[0];
  const float* Wx1 = (const float*)d_in[1];
  const float* Wh1 = (const float*)d_in[2];
  const float* b1  = (const float*)d_in[3];
  const float* Wx2 = (const float*)d_in[4];
  const float* Wh2 = (const float*)d_in[5];
  const float* b2  = (const float*)d_in[6];
  const float* Wd  = (const float*)d_in[7];
  const float* bd  = (const float*)d_in[8];
  float* out = (float*)d_out;

  u16* h1b16 = (u16*)d_ws;                            // [B,T,256] f16 (64 MB)
  float* hfinal = (float*)(h1b16 + (size_t)Bn * Tn * Hn);  // [B,256] f32
  int* flags = (int*)(hfinal + (size_t)Bn * Hn);      // [B] A->BC

  hipMemsetAsync(flags, 0, Bn * sizeof(int), stream);
  stage1_kernel<<<2 * Bn, 1024, 0, stream>>>(x, Wx1, Wh1, b1, Wx2, b2, Wh2,
                                             h1b16, flags, hfinal);
  head_kernel<<<Bn, 128, 0, stream>>>(hfinal, Wd, bd, out);
}

// Round 17
// 824.354 us; speedup vs baseline: 10.6373x; 10.6373x over previous
//
#include <hip/hip_runtime.h>
#include <cstdint>

constexpr int Bn = 128, Tn = 1024, Dn = 64, Hn = 256, On = 128;

typedef __fp16 h2 __attribute__((ext_vector_type(2)));
typedef __fp16 half8_t __attribute__((ext_vector_type(8)));
typedef float f32x4 __attribute__((ext_vector_type(4)));
typedef unsigned short u16;

__device__ __forceinline__ float fast_tanh(float x) {
  float e = __expf(2.0f * x);
  return 1.0f - 2.0f / (e + 1.0f);
}
__device__ __forceinline__ h2 pk2(float a, float b) {
  h2 r; r.x = (__fp16)a; r.y = (__fp16)b; return r;
}
__device__ __forceinline__ unsigned h2bits(h2 v) { return __builtin_bit_cast(unsigned, v); }
__device__ __forceinline__ u16 f2hb(float f) {
  __fp16 h = (__fp16)f; return __builtin_bit_cast(u16, h);
}
__device__ __forceinline__ float hb2f(u16 b) {
  return (float)__builtin_bit_cast(__fp16, b);
}

// ---------------------------------------------------------------------------
// MFMA broadcast matvec (rounds 10-15, absmax-verified). Every lane's A-frag
// covers k = 32kt + 8*(l>>4) + e, independent of l&15 -> all 16 A-rows equal
// h -> D reg 0 = h @ W for this lane's column. A and B use the SAME k-map so
// any intra-tile k-permutation cancels. B-frags (weights) live in AGPRs
// (natural 64/64 split at 1024 threads); MFMA reads them natively (isa §10).
// K=256 version: source in the 20-stride slice layout; 2 chains (32 cols).
// ---------------------------------------------------------------------------
__device__ __forceinline__ void mfma_step(const u16* hcB, int oh, int ol,
                                          const half8_t (&wfr)[16],
                                          float& v0, float& v1) {
  uint2 ra[8], rb[8];
  #pragma unroll
  for (int kt = 0; kt < 8; ++kt) {
    const u16* ap = hcB + 40 * kt + 20 * oh + 8 * ol;
    ra[kt] = *(const uint2*)ap;
    rb[kt] = *(const uint2*)(ap + 4);
  }
  f32x4 ac0 = {0.f, 0.f, 0.f, 0.f}, ac1 = {0.f, 0.f, 0.f, 0.f};
  #pragma unroll
  for (int kt = 0; kt < 8; ++kt) {
    half8_t af = __builtin_bit_cast(
        half8_t, make_uint4(ra[kt].x, ra[kt].y, rb[kt].x, rb[kt].y));
    ac0 = __builtin_amdgcn_mfma_f32_16x16x32_f16(af, wfr[kt], ac0, 0, 0, 0);
    ac1 = __builtin_amdgcn_mfma_f32_16x16x32_f16(af, wfr[8 + kt], ac1, 0, 0, 0);
  }
  v0 = ac0[0];
  v1 = ac1[0];
}
// K=64 version: source row in plain stride-64-half layout (16B aligned);
// uses wfr[0],[1] (chain 0) and wfr[8],[9] (chain 1). Verified round 13.
__device__ __forceinline__ void mv64mf(const u16* xrow, int lq,
                                       const half8_t (&wfr)[16],
                                       float& v0, float& v1) {
  uint4 r0 = *(const uint4*)(xrow + lq);
  uint4 r1 = *(const uint4*)(xrow + 32 + lq);
  half8_t af0 = __builtin_bit_cast(half8_t, r0);
  half8_t af1 = __builtin_bit_cast(half8_t, r1);
  f32x4 a0 = {0.f, 0.f, 0.f, 0.f}, a1 = {0.f, 0.f, 0.f, 0.f};
  a0 = __builtin_amdgcn_mfma_f32_16x16x32_f16(af0, wfr[0], a0, 0, 0, 0);
  a0 = __builtin_amdgcn_mfma_f32_16x16x32_f16(af1, wfr[1], a0, 0, 0, 0);
  a1 = __builtin_amdgcn_mfma_f32_16x16x32_f16(af0, wfr[8], a1, 0, 0, 0);
  a1 = __builtin_amdgcn_mfma_f32_16x16x32_f16(af1, wfr[9], a1, 0, 0, 0);
  v0 = a0[0];
  v1 = a1[0];
}

// LDS h layout (f16): 16 slices x (16 data + 4 pad) halfs; slice stride 40 B.
// ---------------------------------------------------------------------------
// Fused pipeline, 256 WGs x 1024 threads == 1 block/CU. Round-17 = round-16
// (dense waves on the MFMA broadcast matvec, answering the contention-vs-
// barrier A/B) with the SPILL BUG fixed: round 16 unified the weight load
// under a RUNTIME loop bound (kmax = roleA&&!serial ? 2 : 8) -> wfr became
// runtime-indexed -> scratch (rule #20; FETCH 22 GB, 8.7 ms). Here the load
// is back to three branches with COMPILE-TIME bounds, fully unrolled, every
// wfr index static -> registers (round 15: VGPR=64, zero spill).
//   role A  (blocks 0..127): waves 0-7 serial scan1 (Wh1 frags in AGPR);
//       waves 8-15 dense: stage x + u1 = x@Wx1+b1 rows via mv64mf.
//   role BC (blocks 128..255): waves 0-7 serial scan2 (Wh2);
//       waves 8-15 dense u2 = h1@Wx2+b2 via mfma_step.
//   Each wave owns 32 output cols: jc = 32*(w&7) + (l&15), chains at jc and
//   jc+16. wfr[16] = 64 regs -> AGPR half of the 1024-thr 64/64 split.
// ---------------------------------------------------------------------------
__global__ __launch_bounds__(1024)
__attribute__((amdgpu_waves_per_eu(4, 4))) void stage1_kernel(
    const float* __restrict__ x,    // [B,T,64] f32
    const float* __restrict__ Wx1,  // [64,256] f32
    const float* __restrict__ Wh1,  // [256,256] f32
    const float* __restrict__ b1,   // [256]
    const float* __restrict__ Wx2,  // [256,256] f32
    const float* __restrict__ b2,   // [256]
    const float* __restrict__ Wh2,  // [256,256] f32
    u16* __restrict__ h1b16,        // [B,T,256] f16 h1 (A -> BC channel)
    int* __restrict__ flags,        // [B]  A -> BC progress (32-step chunks)
    float* __restrict__ hfinal) {   // [B,256] f32 (role BC output)
  __shared__ alignas(16) u16 smemU[19584];  // 38.25 KB
  const int tid = threadIdx.x;
  const unsigned bid = blockIdx.x;
  const bool roleA = (bid < (unsigned)Bn);
  const bool serialG = (tid < 512);

  // T5 (null in round 15, harmless): serial waves keep priority 1.
  if (serialG) __builtin_amdgcn_s_setprio(1);

  const int w_ = tid >> 6;            // wave 0..15
  const int l = tid & 63;
  const int oh = (l >> 5) & 1;
  const int ol = (l >> 4) & 1;
  const int lq = 8 * (l >> 4);        // k-oct offset (halfs)
  const int jc = 32 * (w_ & 7) + (l & 15);  // wave's chain-0 column
  const int woff0 = 40 * w_ + (l & 15);     // serial h-state write offset
  const int lt = tid & 511;           // index within wave-group

  // ---- weights: frag (g,kt): lane l holds W[32kt+lq+e][jc+16g] ----
  // THREE branches, all with compile-time loop bounds and static wfr
  // indices (rule #20: runtime-indexed ext_vector arrays -> scratch).
  half8_t wfr[16];
  if (serialG) {
    const float* Wser = roleA ? Wh1 : Wh2;
    #pragma unroll
    for (int g = 0; g < 2; ++g)
      #pragma unroll
      for (int kt = 0; kt < 8; ++kt) {
        const float* wp = Wser + (size_t)(32 * kt + lq) * Hn + jc + 16 * g;
        half8_t f;
        #pragma unroll
        for (int e = 0; e < 8; ++e) f[e] = (__fp16)wp[(size_t)e * Hn];
        wfr[g * 8 + kt] = f;
      }
  } else if (roleA) {
    #pragma unroll
    for (int i = 0; i < 16; ++i) wfr[i] = half8_t{0};
    #pragma unroll
    for (int g = 0; g < 2; ++g)
      #pragma unroll
      for (int kt = 0; kt < 2; ++kt) {
        const float* wp = Wx1 + (size_t)(32 * kt + lq) * Hn + jc + 16 * g;
        half8_t f;
        #pragma unroll
        for (int e = 0; e < 8; ++e) f[e] = (__fp16)wp[(size_t)e * Hn];
        wfr[g * 8 + kt] = f;
      }
  } else {
    #pragma unroll
    for (int g = 0; g < 2; ++g)
      #pragma unroll
      for (int kt = 0; kt < 8; ++kt) {
        const float* wp = Wx2 + (size_t)(32 * kt + lq) * Hn + jc + 16 * g;
        half8_t f;
        #pragma unroll
        for (int e = 0; e < 8; ++e) f[e] = (__fp16)wp[(size_t)e * Hn];
        wfr[g * 8 + kt] = f;
      }
  }
  // dense biases for this wave's 2 columns
  float bjd0 = 0.f, bjd1 = 0.f;
  if (!serialG) {
    const float* bb = roleA ? b1 : b2;
    bjd0 = bb[jc];
    bjd1 = bb[jc + 16];
  }

  if (roleA) {
    // ==================== ROLE A ====================
    const int b = bid;
    const float* xb = x + (size_t)b * Tn * Dn;
    u16* hb = h1b16 + (size_t)b * Tn * Hn;
    u16* hcH = smemU;            // 640 halfs: 2 x 320 h-state
    u16* xs = smemU + 640;       // 2048 halfs: x chunk [32][64] f16
    u16* u1S = smemU + 2688;     // 8704 halfs: u1 [32][272]

    if (serialG)
      for (int i = tid; i < 640; i += 512) hcH[i] = 0;
    __syncthreads();

    for (int ch = 0; ch < 32; ++ch) {
      // pre1: dense stages x chunk ch -> xs (f16)
      if (!serialG) {
        const float* xsrc = xb + (size_t)ch * 2048 + (lt >> 4) * 64 + (lt & 15) * 4;
        float4 f = *(const float4*)xsrc;
        *(uint2*)(xs + (lt >> 4) * 64 + (lt & 15) * 4) =
            make_uint2(h2bits(pk2(f.x, f.y)), h2bits(pk2(f.z, f.w)));
      }
      __syncthreads();
      // pre2: dense computes u1 row 0
      if (!serialG) {
        float v0, v1;
        mv64mf(xs, lq, wfr, v0, v1);
        if (l < 16) {
          u1S[jc] = f2hb(v0 + bjd0);
          u1S[jc + 16] = f2hb(v1 + bjd1);
        }
      }
      __syncthreads();
      // 32 slices: serial step s || dense u1 row s+1
      for (int g4 = 0; g4 < 4; ++g4) {
        u16 hreg0[8], hreg1[8];
        #pragma unroll
        for (int s8 = 0; s8 < 8; ++s8) {
          const int s = g4 * 8 + s8;
          if (serialG) {
            const int cu = s & 1, nx = cu ^ 1;
            float uv0 = hb2f(u1S[s * 272 + jc]);
            float uv1 = hb2f(u1S[s * 272 + jc + 16]);
            float v0, v1;
            mfma_step(hcH + cu * 320, oh, ol, wfr, v0, v1);
            u16 h0 = f2hb(fast_tanh(v0 + uv0));
            u16 h1 = f2hb(fast_tanh(v1 + uv1));
            if (l < 16) {
              hcH[nx * 320 + woff0] = h0;
              hcH[nx * 320 + woff0 + 20] = h1;
            }
            hreg0[s8] = h0;
            hreg1[s8] = h1;
            if (s8 == 7 && l < 16) {
              u16* d0 = hb + (size_t)(32 * ch + s - 7) * Hn + jc;
              #pragma unroll
              for (int i = 0; i < 8; ++i) {
                d0[i * Hn] = hreg0[i];
                d0[i * Hn + 16] = hreg1[i];
              }
            }
          } else if (s < 31) {
            float v0, v1;
            mv64mf(xs + (s + 1) * 64, lq, wfr, v0, v1);
            if (l < 16) {
              u1S[(s + 1) * 272 + jc] = f2hb(v0 + bjd0);
              u1S[(s + 1) * 272 + jc + 16] = f2hb(v1 + bjd1);
            }
          }
          __syncthreads();  // drains vmem (incl. h1 stores at s8==7)
        }
      }
      if (tid == 0)
        __hip_atomic_store(flags + b, ch + 1, __ATOMIC_RELEASE,
                           __HIP_MEMORY_SCOPE_AGENT);
    }
  } else {
    // ==================== ROLE BC ====================
    const int b = bid - Bn;
    const u16* hb1 = h1b16 + (size_t)b * Tn * Hn;
    u16* hsH = smemU;            // [32][320] halfs (h1 staging, slice layout)
    u16* u2S = smemU + 10240;    // [32][272] halfs (u2)
    u16* hcU = smemU + 18944;    // 2 x 320 halfs (h2 state)
    u16* ldst = hsH + (lt >> 4) * 320 + 20 * (lt & 15);

    if (serialG)
      for (int i = tid; i < 640; i += 512) hcU[i] = 0;
    __syncthreads();

    for (int ch = 0; ch < 32; ++ch) {
      if (!serialG && lt == 0) {
        while (__hip_atomic_load(flags + b, __ATOMIC_ACQUIRE,
                                 __HIP_MEMORY_SCOPE_AGENT) < ch + 1)
          __builtin_amdgcn_s_sleep(8);
      }
      __syncthreads();  // flag acquired
      if (!serialG) {   // stage h1 chunk [32][256] -> hsH (slice layout)
        const uint4* src =
            (const uint4*)(hb1 + (size_t)(ch * 32 + (lt >> 4)) * Hn + 16 * (lt & 15));
        uint4 v0 = src[0], v1 = src[1];
        ((uint2*)ldst)[0] = make_uint2(v0.x, v0.y);
        ((uint2*)ldst)[1] = make_uint2(v0.z, v0.w);
        ((uint2*)ldst)[2] = make_uint2(v1.x, v1.y);
        ((uint2*)ldst)[3] = make_uint2(v1.z, v1.w);
      }
      __syncthreads();  // staged
      if (!serialG) {   // u2 row 0
        float v0, v1;
        mfma_step(hsH, oh, ol, wfr, v0, v1);
        if (l < 16) {
          u2S[jc] = f2hb(v0 + bjd0);
          u2S[jc + 16] = f2hb(v1 + bjd1);
        }
      }
      __syncthreads();  // row 0 visible

      for (int g4 = 0; g4 < 4; ++g4) {
        #pragma unroll
        for (int s8 = 0; s8 < 8; ++s8) {
          const int s = g4 * 8 + s8;
          if (serialG) {
            const int cu = s & 1, nx = cu ^ 1;
            float uv0 = hb2f(u2S[s * 272 + jc]);
            float uv1 = hb2f(u2S[s * 272 + jc + 16]);
            float v0, v1;
            mfma_step(hcU + cu * 320, oh, ol, wfr, v0, v1);
            if (l < 16) {
              hcU[nx * 320 + woff0] = f2hb(fast_tanh(v0 + uv0));
              hcU[nx * 320 + woff0 + 20] = f2hb(fast_tanh(v1 + uv1));
            }
          } else if (s < 31) {
            float v0, v1;
            mfma_step(hsH + (s + 1) * 320, oh, ol, wfr, v0, v1);
            if (l < 16) {
              u2S[(s + 1) * 272 + jc] = f2hb(v0 + bjd0);
              u2S[(s + 1) * 272 + jc + 16] = f2hb(v1 + bjd1);
            }
          }
          __syncthreads();
        }
      }
    }
    if (tid < Hn)
      hfinal[(size_t)b * Hn + tid] = hb2f(hcU[(tid >> 4) * 20 + (tid & 15)]);
  }
}

// ---------------------------------------------------------------------------
// Head: out = softmax(h2_T @ Wd + bd). f32, unchanged.
// ---------------------------------------------------------------------------
__global__ __launch_bounds__(128) void head_kernel(
    const float* __restrict__ hfinal, const float* __restrict__ Wd,
    const float* __restrict__ bd, float* __restrict__ out) {
  __shared__ float hrow[Hn];
  __shared__ float red[On];
  const int o = threadIdx.x;
  const int b = blockIdx.x;
  hrow[o] = hfinal[(size_t)b * Hn + o];
  hrow[o + 128] = hfinal[(size_t)b * Hn + 128 + o];
  __syncthreads();
  float acc = bd[o];
  #pragma unroll 8
  for (int k = 0; k < Hn; ++k) acc = fmaf(hrow[k], Wd[(size_t)k * On + o], acc);
  red[o] = acc;
  __syncthreads();
  #pragma unroll
  for (int s = 64; s > 0; s >>= 1) {
    if (o < s) red[o] = fmaxf(red[o], red[o + s]);
    __syncthreads();
  }
  const float mx = red[0];
  __syncthreads();
  const float e = __expf(acc - mx);
  red[o] = e;
  __syncthreads();
  #pragma unroll
  for (int s = 64; s > 0; s >>= 1) {
    if (o < s) red[o] += red[o + s];
    __syncthreads();
  }
  out[(size_t)b * On + o] = e / red[0];
}

// ---------------------------------------------------------------------------
extern "C" void kernel_launch(void* const* d_in, const int* in_sizes, int n_in,
                              void* d_out, int out_size, void* d_ws, size_t ws_size,
                              hipStream_t stream) {
  const float* x   = (const float*)d_in[0];
  const float* Wx1 = (const float*)d_in[1];
  const float* Wh1 = (const float*)d_in[2];
  const float* b1  = (const float*)d_in[3];
  const float* Wx2 = (const float*)d_in[4];
  const float* Wh2 = (const float*)d_in[5];
  const float* b2  = (const float*)d_in[6];
  const float* Wd  = (const float*)d_in[7];
  const float* bd  = (const float*)d_in[8];
  float* out = (float*)d_out;

  u16* h1b16 = (u16*)d_ws;                            // [B,T,256] f16 (64 MB)
  float* hfinal = (float*)(h1b16 + (size_t)Bn * Tn * Hn);  // [B,256] f32
  int* flags = (int*)(hfinal + (size_t)Bn * Hn);      // [B] A->BC

  hipMemsetAsync(flags, 0, Bn * sizeof(int), stream);
  stage1_kernel<<<2 * Bn, 1024, 0, stream>>>(x, Wx1, Wh1, b1, Wx2, b2, Wh2,
                                             h1b16, flags, hfinal);
  head_kernel<<<Bn, 128, 0, stream>>>(hfinal, Wd, bd, out);
}